// Round 8
// baseline (228.109 us; speedup 1.0000x reference)
//
#include <hip/hip_runtime.h>
#include <hip/hip_bf16.h>
#include <stdint.h>

typedef float  f32x4  __attribute__((ext_vector_type(4)));
typedef __bf16 bf16x8 __attribute__((ext_vector_type(8)));
typedef unsigned short us4 __attribute__((ext_vector_type(4)));

#define NDIM 4096
#define DDIM 512
#define PSTRIDE 2097152   // 512*4096 = 4096*512 floats per split-K partial

__device__ __forceinline__ unsigned short f2bf(float f) {
    union { float f; uint32_t u; } v; v.f = f;
    uint32_t u = v.u;
    u += 0x7FFFu + ((u >> 16) & 1u);   // round-to-nearest-even
    return (unsigned short)(u >> 16);
}

// Fused prep (block-range dispatch):
//   [0, 16384)      : A fp32 -> bf16 with +I      (4096x4096, float4/thread)
//   [16384, 18432)  : X fp32 -> bf16              (4096x512)
//   [18432, 18688)  : W fp32 -> bf16              (512x512)
//   [18688, 18704)  : ds[i] = rsqrt(A[i,i]+1)
__global__ void prep_kernel(const float* __restrict__ A, const float* __restrict__ X,
                            const float* __restrict__ W,
                            unsigned short* __restrict__ A2, unsigned short* __restrict__ Xb,
                            unsigned short* __restrict__ Wb, float* __restrict__ ds) {
    const int b = blockIdx.x, tid = threadIdx.x;
    if (b < 16384) {
        int i = b * 256 + tid;          // float4 index into A
        int e = i << 2;
        int row = e >> 12, col = e & 4095;
        f32x4 v = ((const f32x4*)A)[i];
        int d = row - col;
        if (d >= 0 && d < 4) v[d] += 1.0f;
        us4 o; o.x = f2bf(v.x); o.y = f2bf(v.y); o.z = f2bf(v.z); o.w = f2bf(v.w);
        ((us4*)A2)[i] = o;
    } else if (b < 18432) {
        int i = (b - 16384) * 256 + tid;
        f32x4 v = ((const f32x4*)X)[i];
        us4 o; o.x = f2bf(v.x); o.y = f2bf(v.y); o.z = f2bf(v.z); o.w = f2bf(v.w);
        ((us4*)Xb)[i] = o;
    } else if (b < 18688) {
        int i = (b - 18432) * 256 + tid;
        f32x4 v = ((const f32x4*)W)[i];
        us4 o; o.x = f2bf(v.x); o.y = f2bf(v.y); o.z = f2bf(v.z); o.w = f2bf(v.w);
        ((us4*)Wb)[i] = o;
    } else {
        int i = (b - 18688) * 256 + tid;
        if (i < NDIM) ds[i] = rsqrtf(A[(size_t)i * (NDIM + 1)] + 1.0f);
    }
}

// C = A @ B^T.  A: [M x K] bf16 row-major, B: [Nr x K] bf16 row-major.
// BM=BN=128; 4 waves (2x2), wave-tile 64x64 (4x4 MFMAs of 16x16x32).
// DIRA/DIRB: that operand is small & L2/L3-resident (4 MB) -> its fragments
// are loaded DIRECTLY from global into registers before the barrier (latency
// hides under the staging drain); only the streamed operand goes through
// global_load_lds.  This halves staged bytes+LDS writes, and BK=128 (32 KB
// LDS for one operand) halves the number of barrier drains per block.
// Grid: (x, y, z); z = K-chunk of size kc.
//   SWAP=0: x = m-tile, y = n-tile.  SWAP=1: x = n-tile, y = m-tile.
//   grid-x walks the LARGE streamed matrix (XCD pinning: linear id % 8 = x % 8).
// MODE 0: store bf16 TRANSPOSED (C_t[n][m], ldc = M), single k-chunk.
// MODE 2: plain fp32 stores into partial buffer C + z*PSTRIDE, row-major [M x ldc].
template <int MODE, int SWAP, int BK, int DIRA, int DIRB>
__global__ __launch_bounds__(256, 2) void gemm_bt(
    const unsigned short* __restrict__ A,
    const unsigned short* __restrict__ B,
    void* __restrict__ C,
    int K, int kc, int ldc)
{
    constexpr int LPR = BK / 8;        // lanes per LDS row (row = BK*2 bytes)
    constexpr int RPI = 64 / LPR;      // rows per staging instruction
    constexpr int IPW = 128 / (4 * RPI); // staging instructions per wave
    constexpr int KS  = BK / 32;       // 32-k MFMA steps per chunk

    __shared__ unsigned short lsA[DIRA ? 64 : 128 * BK];
    __shared__ unsigned short lsB[DIRB ? 64 : 128 * BK];

    const int tid  = threadIdx.x;
    const int wid  = tid >> 6;
    const int lane = tid & 63;
    const int m0 = (SWAP ? blockIdx.y : blockIdx.x) * 128;
    const int n0 = (SWAP ? blockIdx.x : blockIdx.y) * 128;
    const int kbase = blockIdx.z * kc;
    const int wm = (wid & 1) * 64;
    const int wn = (wid >> 1) * 64;
    const int quad = lane >> 4;
    const int c16  = lane & 15;

    // staging geometry: instr i covers LDS rows wid*32 + i*RPI + lrow
    const int lrow = lane / LPR;
    const int lcs  = (lane % LPR) * 16;

    f32x4 acc[4][4];
    #pragma unroll
    for (int i = 0; i < 4; i++)
        #pragma unroll
        for (int j = 0; j < 4; j++) acc[i][j] = (f32x4)0.0f;

    const char* gA = (const char*)A + ((size_t)(m0 + wid * 32 + lrow) * K) * 2 + lcs;
    const char* gB = (const char*)B + ((size_t)(n0 + wid * 32 + lrow) * K) * 2 + lcs;
    const size_t rowstep = (size_t)RPI * K * 2;

    // direct-operand per-lane row pointers (fragment = 16B at quad*16 + ks*64)
    const char* aDir[4];
    const char* bDir[4];
    #pragma unroll
    for (int t = 0; t < 4; t++) {
        if (DIRA) aDir[t] = (const char*)A + ((size_t)(m0 + wm + t * 16 + c16) * K) * 2 + quad * 16;
        if (DIRB) bDir[t] = (const char*)B + ((size_t)(n0 + wn + t * 16 + c16) * K) * 2 + quad * 16;
    }

    for (int k0 = kbase; k0 < kbase + kc; k0 += BK) {
        const size_t kb = (size_t)k0 * 2;
        if (!DIRA) {
            #pragma unroll
            for (int i = 0; i < IPW; i++)
                __builtin_amdgcn_global_load_lds(
                    (const __attribute__((address_space(1))) void*)(gA + kb + (size_t)i * rowstep),
                    (__attribute__((address_space(3))) void*)(&lsA[(wid * IPW + i) * 512]),
                    16, 0, 0);
        }
        if (!DIRB) {
            #pragma unroll
            for (int i = 0; i < IPW; i++)
                __builtin_amdgcn_global_load_lds(
                    (const __attribute__((address_space(1))) void*)(gB + kb + (size_t)i * rowstep),
                    (__attribute__((address_space(3))) void*)(&lsB[(wid * IPW + i) * 512]),
                    16, 0, 0);
        }
        // direct fragment preloads: issued before the barrier so their L2/L3
        // latency overlaps the staging drain.
        bf16x8 apre[KS][4], bpre[KS][4];
        if (DIRA) {
            #pragma unroll
            for (int ks = 0; ks < KS; ks++)
                #pragma unroll
                for (int mt = 0; mt < 4; mt++)
                    apre[ks][mt] = *(const bf16x8*)(aDir[mt] + kb + ks * 64);
        }
        if (DIRB) {
            #pragma unroll
            for (int ks = 0; ks < KS; ks++)
                #pragma unroll
                for (int nt = 0; nt < 4; nt++)
                    bpre[ks][nt] = *(const bf16x8*)(bDir[nt] + kb + ks * 64);
        }
        __syncthreads();

        #pragma unroll
        for (int ks = 0; ks < KS; ks++) {
            const int kboff = ks * 64 + quad * 16;   // byte offset in BK*2-byte row
            bf16x8 bfrag[4], afrag[4];
            #pragma unroll
            for (int nt = 0; nt < 4; nt++) {
                if (DIRB) bfrag[nt] = bpre[ks][nt];
                else {
                    int r = wn + nt * 16 + c16;
                    bfrag[nt] = *(const bf16x8*)((const char*)lsB + r * (BK * 2) + kboff);
                }
            }
            #pragma unroll
            for (int mt = 0; mt < 4; mt++) {
                if (DIRA) afrag[mt] = apre[ks][mt];
                else {
                    int r = wm + mt * 16 + c16;
                    afrag[mt] = *(const bf16x8*)((const char*)lsA + r * (BK * 2) + kboff);
                }
            }
            #pragma unroll
            for (int mt = 0; mt < 4; mt++)
                #pragma unroll
                for (int nt = 0; nt < 4; nt++)
                    acc[mt][nt] = __builtin_amdgcn_mfma_f32_16x16x32_bf16(
                        afrag[mt], bfrag[nt], acc[mt][nt], 0, 0, 0);
        }
        __syncthreads();
    }

    // epilogue.  C/D layout: col = lane&15, row = (lane>>4)*4 + reg
    #pragma unroll
    for (int mt = 0; mt < 4; mt++) {
        const int gm0 = m0 + wm + mt * 16 + quad * 4;   // 4 consecutive rows
        #pragma unroll
        for (int nt = 0; nt < 4; nt++) {
            const int gn = n0 + wn + nt * 16 + c16;
            f32x4 v = acc[mt][nt];
            if (MODE == 0) {
                us4 o;
                o.x = f2bf(v.x); o.y = f2bf(v.y); o.z = f2bf(v.z); o.w = f2bf(v.w);
                *(us4*)((unsigned short*)C + (size_t)gn * ldc + gm0) = o;
            } else {
                float* o = (float*)C + (size_t)blockIdx.z * PSTRIDE + (size_t)gm0 * ldc + gn;
                o[0]               = v.x;
                o[ldc]             = v.y;
                o[2 * (size_t)ldc] = v.z;
                o[3 * (size_t)ldc] = v.w;
            }
        }
    }
}

// T2[j][i] = bf16(ds[i] * sum_z P[z][j][i]).  P: 4 partials [512 x 4096] fp32.
__global__ void ep2_kernel(const float* __restrict__ P, const float* __restrict__ ds,
                           unsigned short* __restrict__ T2) {
    int t = blockIdx.x * 256 + threadIdx.x;
    int e = t << 2;
    int i = e & 4095;                  // column index
    f32x4 v = ((const f32x4*)P)[t];
    v += ((const f32x4*)(P + PSTRIDE))[t];
    v += ((const f32x4*)(P + 2 * PSTRIDE))[t];
    v += ((const f32x4*)(P + 3 * PSTRIDE))[t];
    f32x4 d = *(const f32x4*)(ds + i);
    us4 o;
    o.x = f2bf(v.x * d.x); o.y = f2bf(v.y * d.y);
    o.z = f2bf(v.z * d.z); o.w = f2bf(v.w * d.w);
    ((us4*)T2)[t] = o;
}

// out[i][j] = relu(ds[i] * sum_z Q[z][i][j]).  Q: 4 partials [4096 x 512] fp32.
__global__ void ep3_kernel(const float* __restrict__ Q, const float* __restrict__ ds,
                           float* __restrict__ out) {
    int t = blockIdx.x * 256 + threadIdx.x;
    int e = t << 2;
    int i = e >> 9;                    // row index
    float s = ds[i];
    f32x4 v = ((const f32x4*)Q)[t];
    v += ((const f32x4*)(Q + PSTRIDE))[t];
    v += ((const f32x4*)(Q + 2 * PSTRIDE))[t];
    v += ((const f32x4*)(Q + 3 * PSTRIDE))[t];
    f32x4 o;
    o.x = fmaxf(v.x * s, 0.0f); o.y = fmaxf(v.y * s, 0.0f);
    o.z = fmaxf(v.z * s, 0.0f); o.w = fmaxf(v.w * s, 0.0f);
    ((f32x4*)out)[t] = o;
}

extern "C" void kernel_launch(void* const* d_in, const int* in_sizes, int n_in,
                              void* d_out, int out_size, void* d_ws, size_t ws_size,
                              hipStream_t stream) {
    const float* X = (const float*)d_in[0];   // [4096 x 512]
    const float* A = (const float*)d_in[1];   // [4096 x 4096]
    const float* W = (const float*)d_in[2];   // [512 x 512]

    char* ws = (char*)d_ws;
    float*          dsc  = (float*)ws;                           // 16 KB
    unsigned short* A2   = (unsigned short*)(ws + 16384);        // 32 MB   bf16 A+I
    unsigned short* Xb   = (unsigned short*)(ws + 33570816u);    // 4 MB
    unsigned short* Wb   = (unsigned short*)(ws + 37765120u);    // 512 KB
    unsigned short* Yt   = (unsigned short*)(ws + 38289408u);    // 4 MB    (X@W^T)^T  [512][4096]
    unsigned short* T2   = (unsigned short*)(ws + 42483712u);    // 4 MB    ds*(A2@Y) transposed [512][4096]
    float*          Part = (float*)(ws + 46678016u);             // 32 MB   4 x fp32 split-K partials

    prep_kernel<<<18704, 256, 0, stream>>>(A, X, W, A2, Xb, Wb, dsc);

    // Yt = (Xb @ Wb^T)^T  [512][4096] bf16.  M=4096 (32 m-tiles = grid-x), N=512 (4 n-tiles).
    gemm_bt<0, 0, 64, 0, 0><<<dim3(32, 4, 1), 256, 0, stream>>>(Xb, Wb, Yt, 512, 512, 4096);
    // Part[z][512][4096] = Yt @ A2^T partials.  A=Yt DIRECT (4 MB), B=A2 staged, BK=128.
    gemm_bt<2, 1, 128, 1, 0><<<dim3(32, 4, 4), 256, 0, stream>>>(Yt, A2, Part, 4096, 1024, 4096);
    // T2 = bf16(ds_col * sum_z Part[z]).
    ep2_kernel<<<2048, 256, 0, stream>>>(Part, dsc, T2);
    // Part[z][4096][512] = A2 @ T2^T partials.  A=A2 staged, B=T2 DIRECT (4 MB), BK=128.
    gemm_bt<2, 0, 128, 0, 1><<<dim3(32, 4, 4), 256, 0, stream>>>(A2, T2, Part, 4096, 1024, 512);
    // out = relu(ds_row * sum_z Part[z])  [4096 x 512] fp32.
    ep3_kernel<<<2048, 256, 0, stream>>>(Part, dsc, (float*)d_out);
}

// Round 9
// 198.710 us; speedup vs baseline: 1.1479x; 1.1479x over previous
//
#include <hip/hip_runtime.h>
#include <hip/hip_bf16.h>
#include <stdint.h>

typedef float  f32x4  __attribute__((ext_vector_type(4)));
typedef __bf16 bf16x8 __attribute__((ext_vector_type(8)));
typedef unsigned short us4 __attribute__((ext_vector_type(4)));

#define NDIM 4096
#define DDIM 512
#define PSTRIDE 2097152   // 512*4096 = 4096*512 floats per split-K partial
#define NPART 8           // split-K factor for the two big GEMMs

__device__ __forceinline__ unsigned short f2bf(float f) {
    union { float f; uint32_t u; } v; v.f = f;
    uint32_t u = v.u;
    u += 0x7FFFu + ((u >> 16) & 1u);   // round-to-nearest-even
    return (unsigned short)(u >> 16);
}

// Fused prep (block-range dispatch):
//   [0, 16384)      : A fp32 -> bf16 with +I      (4096x4096, float4/thread)
//   [16384, 18432)  : X fp32 -> bf16              (4096x512)
//   [18432, 18688)  : W fp32 -> bf16              (512x512)
//   [18688, 18704)  : ds[i] = rsqrt(A[i,i]+1)
__global__ void prep_kernel(const float* __restrict__ A, const float* __restrict__ X,
                            const float* __restrict__ W,
                            unsigned short* __restrict__ A2, unsigned short* __restrict__ Xb,
                            unsigned short* __restrict__ Wb, float* __restrict__ ds) {
    const int b = blockIdx.x, tid = threadIdx.x;
    if (b < 16384) {
        int i = b * 256 + tid;          // float4 index into A
        int e = i << 2;
        int row = e >> 12, col = e & 4095;
        f32x4 v = ((const f32x4*)A)[i];
        int d = row - col;
        if (d >= 0 && d < 4) v[d] += 1.0f;
        us4 o; o.x = f2bf(v.x); o.y = f2bf(v.y); o.z = f2bf(v.z); o.w = f2bf(v.w);
        ((us4*)A2)[i] = o;
    } else if (b < 18432) {
        int i = (b - 16384) * 256 + tid;
        f32x4 v = ((const f32x4*)X)[i];
        us4 o; o.x = f2bf(v.x); o.y = f2bf(v.y); o.z = f2bf(v.z); o.w = f2bf(v.w);
        ((us4*)Xb)[i] = o;
    } else if (b < 18688) {
        int i = (b - 18432) * 256 + tid;
        f32x4 v = ((const f32x4*)W)[i];
        us4 o; o.x = f2bf(v.x); o.y = f2bf(v.y); o.z = f2bf(v.z); o.w = f2bf(v.w);
        ((us4*)Wb)[i] = o;
    } else {
        int i = (b - 18688) * 256 + tid;
        if (i < NDIM) ds[i] = rsqrtf(A[(size_t)i * (NDIM + 1)] + 1.0f);
    }
}

// C = A @ B^T.  A: [M x K] bf16 row-major, B: [Nr x K] bf16 row-major.
// BM=BN=128, BK=64, 4 waves (2x2), wave-tile 64x64 (4x4 MFMAs of 16x16x32).
// m97-style LINEAR staging (r8 showed: direct-from-global fragments and
// BK=128 linear both regress).  Plain-store split-K partials (no atomics).
// Staging throughput model (r3/r6/r7): ~6 TB/s at 2 blocks/CU, ~12 TB/s at
// 8 blocks/CU -> z=NPART=8 gives 1024 blocks = 4/CU for the big GEMMs.
// Grid: (x, y, z); z = K-chunk of size kc.
//   SWAP=0: x = m-tile, y = n-tile.  SWAP=1: x = n-tile, y = m-tile.
//   grid-x walks the LARGE streamed matrix (XCD pinning: linear id % 8 = x % 8;
//   32 and 128 divisible by 8 so y,z don't perturb the XCD).
// MODE 0: store bf16 TRANSPOSED (C_t[n][m], ldc = M), single k-chunk.
// MODE 2: plain fp32 stores into partial buffer C + z*PSTRIDE, row-major [M x ldc].
template <int MODE, int SWAP>
__global__ __launch_bounds__(256, 4) void gemm_bt(
    const unsigned short* __restrict__ A,
    const unsigned short* __restrict__ B,
    void* __restrict__ C,
    int K, int kc, int ldc)
{
    __shared__ unsigned short lsA[128 * 64];  // 16 KB, rows of 128 B, linear
    __shared__ unsigned short lsB[128 * 64];  // 16 KB

    const int tid  = threadIdx.x;
    const int wid  = tid >> 6;
    const int lane = tid & 63;
    const int m0 = (SWAP ? blockIdx.y : blockIdx.x) * 128;
    const int n0 = (SWAP ? blockIdx.x : blockIdx.y) * 128;
    const int kbase = blockIdx.z * kc;
    const int wm = (wid & 1) * 64;
    const int wn = (wid >> 1) * 64;

    // staging: instr t covers LDS rows t*8+(l>>3), 16B col (l&7) — LINEAR.
    const int lrow = lane >> 3;
    const int lcs  = (lane & 7) * 16;

    f32x4 acc[4][4];
    #pragma unroll
    for (int i = 0; i < 4; i++)
        #pragma unroll
        for (int j = 0; j < 4; j++) acc[i][j] = (f32x4)0.0f;

    // instr t = wid*4+i -> global rows m0 + wid*32 + i*8 + lrow
    const char* gA = (const char*)A + ((size_t)(m0 + wid * 32 + lrow) * K) * 2 + lcs;
    const char* gB = (const char*)B + ((size_t)(n0 + wid * 32 + lrow) * K) * 2 + lcs;
    const size_t rowstep = (size_t)8 * K * 2;

    for (int k0 = kbase; k0 < kbase + kc; k0 += 64) {
        const size_t kb = (size_t)k0 * 2;
        #pragma unroll
        for (int i = 0; i < 4; i++) {
            __builtin_amdgcn_global_load_lds(
                (const __attribute__((address_space(1))) void*)(gA + kb + (size_t)i * rowstep),
                (__attribute__((address_space(3))) void*)(&lsA[(wid * 4 + i) * 512]),
                16, 0, 0);
            __builtin_amdgcn_global_load_lds(
                (const __attribute__((address_space(1))) void*)(gB + kb + (size_t)i * rowstep),
                (__attribute__((address_space(3))) void*)(&lsB[(wid * 4 + i) * 512]),
                16, 0, 0);
        }
        __syncthreads();

        #pragma unroll
        for (int ks = 0; ks < 2; ks++) {
            const int kboff = ks * 64 + (lane >> 4) * 16;  // byte offset in 128B row
            bf16x8 bfrag[4], afrag[4];
            #pragma unroll
            for (int nt = 0; nt < 4; nt++) {
                int r = wn + nt * 16 + (lane & 15);
                bfrag[nt] = *(const bf16x8*)((const char*)lsB + r * 128 + kboff);
            }
            #pragma unroll
            for (int mt = 0; mt < 4; mt++) {
                int r = wm + mt * 16 + (lane & 15);
                afrag[mt] = *(const bf16x8*)((const char*)lsA + r * 128 + kboff);
            }
            #pragma unroll
            for (int mt = 0; mt < 4; mt++)
                #pragma unroll
                for (int nt = 0; nt < 4; nt++)
                    acc[mt][nt] = __builtin_amdgcn_mfma_f32_16x16x32_bf16(
                        afrag[mt], bfrag[nt], acc[mt][nt], 0, 0, 0);
        }
        __syncthreads();
    }

    // epilogue.  C/D layout: col = lane&15, row = (lane>>4)*4 + reg
    const int col  = lane & 15;
    const int quad = lane >> 4;
    #pragma unroll
    for (int mt = 0; mt < 4; mt++) {
        const int gm0 = m0 + wm + mt * 16 + quad * 4;   // 4 consecutive rows
        #pragma unroll
        for (int nt = 0; nt < 4; nt++) {
            const int gn = n0 + wn + nt * 16 + col;
            f32x4 v = acc[mt][nt];
            if (MODE == 0) {
                us4 o;
                o.x = f2bf(v.x); o.y = f2bf(v.y); o.z = f2bf(v.z); o.w = f2bf(v.w);
                *(us4*)((unsigned short*)C + (size_t)gn * ldc + gm0) = o;
            } else {
                float* o = (float*)C + (size_t)blockIdx.z * PSTRIDE + (size_t)gm0 * ldc + gn;
                o[0]               = v.x;
                o[ldc]             = v.y;
                o[2 * (size_t)ldc] = v.z;
                o[3 * (size_t)ldc] = v.w;
            }
        }
    }
}

// T2[j][i] = bf16(ds[i] * sum_z P[z][j][i]).  P: NPART partials [512 x 4096] fp32.
__global__ void ep2_kernel(const float* __restrict__ P, const float* __restrict__ ds,
                           unsigned short* __restrict__ T2) {
    int t = blockIdx.x * 256 + threadIdx.x;
    int e = t << 2;
    int i = e & 4095;                  // column index
    f32x4 v = ((const f32x4*)P)[t];
    #pragma unroll
    for (int z = 1; z < NPART; z++)
        v += ((const f32x4*)(P + (size_t)z * PSTRIDE))[t];
    f32x4 d = *(const f32x4*)(ds + i);
    us4 o;
    o.x = f2bf(v.x * d.x); o.y = f2bf(v.y * d.y);
    o.z = f2bf(v.z * d.z); o.w = f2bf(v.w * d.w);
    ((us4*)T2)[t] = o;
}

// out[i][j] = relu(ds[i] * sum_z Q[z][i][j]).  Q: NPART partials [4096 x 512] fp32.
__global__ void ep3_kernel(const float* __restrict__ Q, const float* __restrict__ ds,
                           float* __restrict__ out) {
    int t = blockIdx.x * 256 + threadIdx.x;
    int e = t << 2;
    int i = e >> 9;                    // row index
    float s = ds[i];
    f32x4 v = ((const f32x4*)Q)[t];
    #pragma unroll
    for (int z = 1; z < NPART; z++)
        v += ((const f32x4*)(Q + (size_t)z * PSTRIDE))[t];
    f32x4 o;
    o.x = fmaxf(v.x * s, 0.0f); o.y = fmaxf(v.y * s, 0.0f);
    o.z = fmaxf(v.z * s, 0.0f); o.w = fmaxf(v.w * s, 0.0f);
    ((f32x4*)out)[t] = o;
}

extern "C" void kernel_launch(void* const* d_in, const int* in_sizes, int n_in,
                              void* d_out, int out_size, void* d_ws, size_t ws_size,
                              hipStream_t stream) {
    const float* X = (const float*)d_in[0];   // [4096 x 512]
    const float* A = (const float*)d_in[1];   // [4096 x 4096]
    const float* W = (const float*)d_in[2];   // [512 x 512]

    char* ws = (char*)d_ws;
    float*          dsc  = (float*)ws;                           // 16 KB
    unsigned short* A2   = (unsigned short*)(ws + 16384);        // 32 MB   bf16 A+I
    unsigned short* Xb   = (unsigned short*)(ws + 33570816u);    // 4 MB
    unsigned short* Wb   = (unsigned short*)(ws + 37765120u);    // 512 KB
    unsigned short* Yt   = (unsigned short*)(ws + 38289408u);    // 4 MB    (X@W^T)^T  [512][4096]
    unsigned short* T2   = (unsigned short*)(ws + 42483712u);    // 4 MB    ds*(A2@Y) transposed [512][4096]
    float*          Part = (float*)(ws + 46678016u);             // 64 MB   NPART x fp32 split-K partials

    prep_kernel<<<18704, 256, 0, stream>>>(A, X, W, A2, Xb, Wb, dsc);

    // Yt = (Xb @ Wb^T)^T  [512][4096] bf16.  M=4096 (32 m-tiles = grid-x), N=512 (4 n-tiles).
    gemm_bt<0, 0><<<dim3(32, 4, 1), 256, 0, stream>>>(Xb, Wb, Yt, 512, 512, 4096);
    // Part[z][512][4096] = Yt @ A2^T partials (M=512: 4 m-tiles=y; N=4096: 32 n-tiles=x; z=8).
    gemm_bt<2, 1><<<dim3(32, 4, NPART), 256, 0, stream>>>(Yt, A2, Part, 4096, 4096 / NPART, 4096);
    // T2 = bf16(ds_col * sum_z Part[z]).
    ep2_kernel<<<2048, 256, 0, stream>>>(Part, dsc, T2);
    // Part[z][4096][512] = A2 @ T2^T partials (M=4096: 32 m-tiles=x; N=512: 4 n-tiles=y; z=8).
    gemm_bt<2, 0><<<dim3(32, 4, NPART), 256, 0, stream>>>(A2, T2, Part, 4096, 4096 / NPART, 512);
    // out = relu(ds_row * sum_z Part[z])  [4096 x 512] fp32.
    ep3_kernel<<<2048, 256, 0, stream>>>(Part, dsc, (float*)d_out);
}

// Round 10
// 184.383 us; speedup vs baseline: 1.2371x; 1.0777x over previous
//
#include <hip/hip_runtime.h>
#include <hip/hip_bf16.h>
#include <stdint.h>

typedef float  f32x4  __attribute__((ext_vector_type(4)));
typedef __bf16 bf16x8 __attribute__((ext_vector_type(8)));
typedef unsigned short us4 __attribute__((ext_vector_type(4)));

#define NDIM 4096
#define DDIM 512
#define PSTRIDE 2097152   // elements per split-K partial (512*4096 = 4096*512)
#define NPART 4           // split-K factor for the two big GEMMs

__device__ __forceinline__ unsigned short f2bf(float f) {
    union { float f; uint32_t u; } v; v.f = f;
    uint32_t u = v.u;
    u += 0x7FFFu + ((u >> 16) & 1u);   // round-to-nearest-even
    return (unsigned short)(u >> 16);
}

__device__ __forceinline__ float b2f(unsigned short s) {
    union { uint32_t u; float f; } v; v.u = (uint32_t)s << 16; return v.f;
}

__device__ __forceinline__ f32x4 us4tof(us4 u) {
    f32x4 r; r.x = b2f(u.x); r.y = b2f(u.y); r.z = b2f(u.z); r.w = b2f(u.w);
    return r;
}

// Fused prep (block-range dispatch):
//   [0, 16384)      : A fp32 -> bf16 with +I      (4096x4096, float4/thread)
//   [16384, 18432)  : X fp32 -> bf16              (4096x512)
//   [18432, 18688)  : W fp32 -> bf16              (512x512)
//   [18688, 18704)  : ds[i] = rsqrt(A[i,i]+1)
__global__ void prep_kernel(const float* __restrict__ A, const float* __restrict__ X,
                            const float* __restrict__ W,
                            unsigned short* __restrict__ A2, unsigned short* __restrict__ Xb,
                            unsigned short* __restrict__ Wb, float* __restrict__ ds) {
    const int b = blockIdx.x, tid = threadIdx.x;
    if (b < 16384) {
        int i = b * 256 + tid;          // float4 index into A
        int e = i << 2;
        int row = e >> 12, col = e & 4095;
        f32x4 v = ((const f32x4*)A)[i];
        int d = row - col;
        if (d >= 0 && d < 4) v[d] += 1.0f;
        us4 o; o.x = f2bf(v.x); o.y = f2bf(v.y); o.z = f2bf(v.z); o.w = f2bf(v.w);
        ((us4*)A2)[i] = o;
    } else if (b < 18432) {
        int i = (b - 16384) * 256 + tid;
        f32x4 v = ((const f32x4*)X)[i];
        us4 o; o.x = f2bf(v.x); o.y = f2bf(v.y); o.z = f2bf(v.z); o.w = f2bf(v.w);
        ((us4*)Xb)[i] = o;
    } else if (b < 18688) {
        int i = (b - 18432) * 256 + tid;
        f32x4 v = ((const f32x4*)W)[i];
        us4 o; o.x = f2bf(v.x); o.y = f2bf(v.y); o.z = f2bf(v.z); o.w = f2bf(v.w);
        ((us4*)Wb)[i] = o;
    } else {
        int i = (b - 18688) * 256 + tid;
        if (i < NDIM) ds[i] = rsqrtf(A[(size_t)i * (NDIM + 1)] + 1.0f);
    }
}

// C = A @ B^T.  A: [M x K] bf16 row-major, B: [Nr x K] bf16 row-major.
// BM=BN=128, BK=64, 4 waves (2x2), wave-tile 64x64 (4x4 MFMAs of 16x16x32).
// m97-style LINEAR staging.  Split-K partials stored as BF16 (halves the
// partial write traffic and the epilogue read traffic vs fp32).
// Grid: (x, y, z); z = K-chunk of size kc.
//   SWAP=0: x = m-tile, y = n-tile.  SWAP=1: x = n-tile, y = m-tile.
//   grid-x walks the LARGE streamed matrix (XCD pinning: linear id % 8 = x % 8).
// MODE 0: store bf16 TRANSPOSED (C_t[n][m], ldc = M), single k-chunk.
// MODE 2: bf16 stores into partial buffer C + z*PSTRIDE, row-major [M x ldc].
template <int MODE, int SWAP>
__global__ __launch_bounds__(256, 4) void gemm_bt(
    const unsigned short* __restrict__ A,
    const unsigned short* __restrict__ B,
    void* __restrict__ C,
    int K, int kc, int ldc)
{
    __shared__ unsigned short lsA[128 * 64];  // 16 KB, rows of 128 B, linear
    __shared__ unsigned short lsB[128 * 64];  // 16 KB

    const int tid  = threadIdx.x;
    const int wid  = tid >> 6;
    const int lane = tid & 63;
    const int m0 = (SWAP ? blockIdx.y : blockIdx.x) * 128;
    const int n0 = (SWAP ? blockIdx.x : blockIdx.y) * 128;
    const int kbase = blockIdx.z * kc;
    const int wm = (wid & 1) * 64;
    const int wn = (wid >> 1) * 64;

    // staging: instr t covers LDS rows t*8+(l>>3), 16B col (l&7) — LINEAR.
    const int lrow = lane >> 3;
    const int lcs  = (lane & 7) * 16;

    f32x4 acc[4][4];
    #pragma unroll
    for (int i = 0; i < 4; i++)
        #pragma unroll
        for (int j = 0; j < 4; j++) acc[i][j] = (f32x4)0.0f;

    // instr t = wid*4+i -> global rows m0 + wid*32 + i*8 + lrow
    const char* gA = (const char*)A + ((size_t)(m0 + wid * 32 + lrow) * K) * 2 + lcs;
    const char* gB = (const char*)B + ((size_t)(n0 + wid * 32 + lrow) * K) * 2 + lcs;
    const size_t rowstep = (size_t)8 * K * 2;

    for (int k0 = kbase; k0 < kbase + kc; k0 += 64) {
        const size_t kb = (size_t)k0 * 2;
        #pragma unroll
        for (int i = 0; i < 4; i++) {
            __builtin_amdgcn_global_load_lds(
                (const __attribute__((address_space(1))) void*)(gA + kb + (size_t)i * rowstep),
                (__attribute__((address_space(3))) void*)(&lsA[(wid * 4 + i) * 512]),
                16, 0, 0);
            __builtin_amdgcn_global_load_lds(
                (const __attribute__((address_space(1))) void*)(gB + kb + (size_t)i * rowstep),
                (__attribute__((address_space(3))) void*)(&lsB[(wid * 4 + i) * 512]),
                16, 0, 0);
        }
        __syncthreads();

        #pragma unroll
        for (int ks = 0; ks < 2; ks++) {
            const int kboff = ks * 64 + (lane >> 4) * 16;  // byte offset in 128B row
            bf16x8 bfrag[4], afrag[4];
            #pragma unroll
            for (int nt = 0; nt < 4; nt++) {
                int r = wn + nt * 16 + (lane & 15);
                bfrag[nt] = *(const bf16x8*)((const char*)lsB + r * 128 + kboff);
            }
            #pragma unroll
            for (int mt = 0; mt < 4; mt++) {
                int r = wm + mt * 16 + (lane & 15);
                afrag[mt] = *(const bf16x8*)((const char*)lsA + r * 128 + kboff);
            }
            #pragma unroll
            for (int mt = 0; mt < 4; mt++)
                #pragma unroll
                for (int nt = 0; nt < 4; nt++)
                    acc[mt][nt] = __builtin_amdgcn_mfma_f32_16x16x32_bf16(
                        afrag[mt], bfrag[nt], acc[mt][nt], 0, 0, 0);
        }
        __syncthreads();
    }

    // epilogue.  C/D layout: col = lane&15, row = (lane>>4)*4 + reg
    const int col  = lane & 15;
    const int quad = lane >> 4;
    #pragma unroll
    for (int mt = 0; mt < 4; mt++) {
        const int gm0 = m0 + wm + mt * 16 + quad * 4;   // 4 consecutive rows
        #pragma unroll
        for (int nt = 0; nt < 4; nt++) {
            const int gn = n0 + wn + nt * 16 + col;
            f32x4 v = acc[mt][nt];
            if (MODE == 0) {
                us4 o;
                o.x = f2bf(v.x); o.y = f2bf(v.y); o.z = f2bf(v.z); o.w = f2bf(v.w);
                *(us4*)((unsigned short*)C + (size_t)gn * ldc + gm0) = o;
            } else {
                unsigned short* o = (unsigned short*)C + (size_t)blockIdx.z * PSTRIDE
                                  + (size_t)gm0 * ldc + gn;
                o[0]               = f2bf(v.x);
                o[ldc]             = f2bf(v.y);
                o[2 * (size_t)ldc] = f2bf(v.z);
                o[3 * (size_t)ldc] = f2bf(v.w);
            }
        }
    }
}

// T2[j][i] = bf16(ds[i] * sum_z P[z][j][i]).  P: NPART bf16 partials [512 x 4096].
__global__ void ep2_kernel(const unsigned short* __restrict__ P, const float* __restrict__ ds,
                           unsigned short* __restrict__ T2) {
    int t = blockIdx.x * 256 + threadIdx.x;
    int e = t << 2;
    int i = e & 4095;                  // column index
    f32x4 v = us4tof(((const us4*)P)[t]);
    #pragma unroll
    for (int z = 1; z < NPART; z++)
        v += us4tof(((const us4*)(P + (size_t)z * PSTRIDE))[t]);
    f32x4 d = *(const f32x4*)(ds + i);
    us4 o;
    o.x = f2bf(v.x * d.x); o.y = f2bf(v.y * d.y);
    o.z = f2bf(v.z * d.z); o.w = f2bf(v.w * d.w);
    ((us4*)T2)[t] = o;
}

// out[i][j] = relu(ds[i] * sum_z Q[z][i][j]).  Q: NPART bf16 partials [4096 x 512].
__global__ void ep3_kernel(const unsigned short* __restrict__ Q, const float* __restrict__ ds,
                           float* __restrict__ out) {
    int t = blockIdx.x * 256 + threadIdx.x;
    int e = t << 2;
    int i = e >> 9;                    // row index
    float s = ds[i];
    f32x4 v = us4tof(((const us4*)Q)[t]);
    #pragma unroll
    for (int z = 1; z < NPART; z++)
        v += us4tof(((const us4*)(Q + (size_t)z * PSTRIDE))[t]);
    f32x4 o;
    o.x = fmaxf(v.x * s, 0.0f); o.y = fmaxf(v.y * s, 0.0f);
    o.z = fmaxf(v.z * s, 0.0f); o.w = fmaxf(v.w * s, 0.0f);
    ((f32x4*)out)[t] = o;
}

extern "C" void kernel_launch(void* const* d_in, const int* in_sizes, int n_in,
                              void* d_out, int out_size, void* d_ws, size_t ws_size,
                              hipStream_t stream) {
    const float* X = (const float*)d_in[0];   // [4096 x 512]
    const float* A = (const float*)d_in[1];   // [4096 x 4096]
    const float* W = (const float*)d_in[2];   // [512 x 512]

    char* ws = (char*)d_ws;
    float*          dsc  = (float*)ws;                           // 16 KB
    unsigned short* A2   = (unsigned short*)(ws + 16384);        // 32 MB   bf16 A+I
    unsigned short* Xb   = (unsigned short*)(ws + 33570816u);    // 4 MB
    unsigned short* Wb   = (unsigned short*)(ws + 37765120u);    // 512 KB
    unsigned short* Yt   = (unsigned short*)(ws + 38289408u);    // 4 MB    (X@W^T)^T  [512][4096]
    unsigned short* T2   = (unsigned short*)(ws + 42483712u);    // 4 MB    ds*(A2@Y) transposed [512][4096]
    unsigned short* Part = (unsigned short*)(ws + 46678016u);    // 16 MB   NPART x bf16 split-K partials

    prep_kernel<<<18704, 256, 0, stream>>>(A, X, W, A2, Xb, Wb, dsc);

    // Yt = (Xb @ Wb^T)^T  [512][4096] bf16.  M=4096 (32 m-tiles = grid-x), N=512 (4 n-tiles).
    gemm_bt<0, 0><<<dim3(32, 4, 1), 256, 0, stream>>>(Xb, Wb, Yt, 512, 512, 4096);
    // Part[z][512][4096] = Yt @ A2^T bf16 partials (M=512: 4 m-tiles=y; N=4096: 32 n-tiles=x; z=4).
    gemm_bt<2, 1><<<dim3(32, 4, NPART), 256, 0, stream>>>(Yt, A2, Part, 4096, 4096 / NPART, 4096);
    // T2 = bf16(ds_col * sum_z Part[z]).
    ep2_kernel<<<2048, 256, 0, stream>>>(Part, dsc, T2);
    // Part[z][4096][512] = A2 @ T2^T bf16 partials (M=4096: 32 m-tiles=x; N=512: 4 n-tiles=y; z=4).
    gemm_bt<2, 0><<<dim3(32, 4, NPART), 256, 0, stream>>>(A2, T2, Part, 4096, 4096 / NPART, 512);
    // out = relu(ds_row * sum_z Part[z])  [4096 x 512] fp32.
    ep3_kernel<<<2048, 256, 0, stream>>>(Part, dsc, (float*)d_out);
}

// Round 11
// 167.010 us; speedup vs baseline: 1.3658x; 1.1040x over previous
//
#include <hip/hip_runtime.h>
#include <hip/hip_bf16.h>
#include <stdint.h>

typedef float  f32x4  __attribute__((ext_vector_type(4)));
typedef __bf16 bf16x8 __attribute__((ext_vector_type(8)));
typedef unsigned short us4 __attribute__((ext_vector_type(4)));

#define NDIM 4096
#define DDIM 512
#define PSTRIDE 2097152   // elements per split-K partial (512*4096 = 4096*512)
#define NPART 4           // split-K factor for the two big GEMMs

__device__ __forceinline__ unsigned short f2bf(float f) {
    union { float f; uint32_t u; } v; v.f = f;
    uint32_t u = v.u;
    u += 0x7FFFu + ((u >> 16) & 1u);   // round-to-nearest-even
    return (unsigned short)(u >> 16);
}

__device__ __forceinline__ float b2f(unsigned short s) {
    union { uint32_t u; float f; } v; v.u = (uint32_t)s << 16; return v.f;
}

__device__ __forceinline__ f32x4 us4tof(us4 u) {
    f32x4 r; r.x = b2f(u.x); r.y = b2f(u.y); r.z = b2f(u.z); r.w = b2f(u.w);
    return r;
}

// Fused prep (block-range dispatch):
//   [0, 16384)      : A fp32 -> bf16 with +I      (4096x4096, float4/thread)
//   [16384, 18432)  : X fp32 -> bf16              (4096x512)
//   [18432, 18688)  : W fp32 -> bf16              (512x512)
//   [18688, 18704)  : ds[i] = rsqrt(A[i,i]+1)
__global__ void prep_kernel(const float* __restrict__ A, const float* __restrict__ X,
                            const float* __restrict__ W,
                            unsigned short* __restrict__ A2, unsigned short* __restrict__ Xb,
                            unsigned short* __restrict__ Wb, float* __restrict__ ds) {
    const int b = blockIdx.x, tid = threadIdx.x;
    if (b < 16384) {
        int i = b * 256 + tid;          // float4 index into A
        int e = i << 2;
        int row = e >> 12, col = e & 4095;
        f32x4 v = ((const f32x4*)A)[i];
        int d = row - col;
        if (d >= 0 && d < 4) v[d] += 1.0f;
        us4 o; o.x = f2bf(v.x); o.y = f2bf(v.y); o.z = f2bf(v.z); o.w = f2bf(v.w);
        ((us4*)A2)[i] = o;
    } else if (b < 18432) {
        int i = (b - 16384) * 256 + tid;
        f32x4 v = ((const f32x4*)X)[i];
        us4 o; o.x = f2bf(v.x); o.y = f2bf(v.y); o.z = f2bf(v.z); o.w = f2bf(v.w);
        ((us4*)Xb)[i] = o;
    } else if (b < 18688) {
        int i = (b - 18432) * 256 + tid;
        f32x4 v = ((const f32x4*)W)[i];
        us4 o; o.x = f2bf(v.x); o.y = f2bf(v.y); o.z = f2bf(v.z); o.w = f2bf(v.w);
        ((us4*)Wb)[i] = o;
    } else {
        int i = (b - 18688) * 256 + tid;
        if (i < NDIM) ds[i] = rsqrtf(A[(size_t)i * (NDIM + 1)] + 1.0f);
    }
}

// C = A @ B^T.  A: [M x K] bf16 row-major, B: [Nr x K] bf16 row-major.
// BM=BN=128, BK=128: 8 iters/block at z=4 -> HALF the barrier drains of BK=64.
// XOR(r&7) swizzle at 16B granularity: LDS row r, logical chunk c lives at
// phys chunk c^(r&7).  Fragment reads hit 8 distinct bank-groups (2-way = free,
// m136); staging coalescing intact (per 16-lane row-segment the XOR key is
// constant, so 4/8-lane groups cover aligned 64/128B segments exactly).
// 4 waves (2x2), wave-tile 64x64 (4x4 MFMAs of 16x16x32).
// Grid: (x, y, z); z = K-chunk of size kc.
//   SWAP=0: x = m-tile, y = n-tile.  SWAP=1: x = n-tile, y = m-tile.
//   grid-x walks the LARGE streamed matrix (XCD pinning: linear id % 8 = x % 8).
// MODE 0: store bf16 TRANSPOSED (C_t[n][m], ldc = M), single k-chunk.
// MODE 2: bf16 stores into partial buffer C + z*PSTRIDE, row-major [M x ldc].
template <int MODE, int SWAP>
__global__ __launch_bounds__(256, 2) void gemm_bt(
    const unsigned short* __restrict__ A,
    const unsigned short* __restrict__ B,
    void* __restrict__ C,
    int K, int kc, int ldc)
{
    // BK=128: rows of 256B, 128 rows per operand = 32 KB each
    __shared__ unsigned short lsA[128 * 128];
    __shared__ unsigned short lsB[128 * 128];

    const int tid  = threadIdx.x;
    const int wid  = tid >> 6;
    const int lane = tid & 63;
    const int m0 = (SWAP ? blockIdx.y : blockIdx.x) * 128;
    const int n0 = (SWAP ? blockIdx.x : blockIdx.y) * 128;
    const int kbase = blockIdx.z * kc;
    const int wm = (wid & 1) * 64;
    const int wn = (wid >> 1) * 64;
    const int quad = lane >> 4;
    const int c16  = lane & 15;

    // staging geometry (BK=128): 16 lanes per 256B row, 4 rows per instr,
    // 8 instrs per wave per operand.  instr i covers LDS rows wid*32+i*4+lr.
    const int lr    = lane >> 4;        // row within instr (0..3)
    const int chunk = lane & 15;        // 16B chunk within row
    // XOR key for LDS row R = wid*32 + i*4 + lr:  R&7 = (i&1)*4 + lr
    const int offe = ((chunk ^ lr) * 16);        // i even: key = lr
    // i odd: key = lr+4 -> offset = offe ^ 64

    f32x4 acc[4][4];
    #pragma unroll
    for (int i = 0; i < 4; i++)
        #pragma unroll
        for (int j = 0; j < 4; j++) acc[i][j] = (f32x4)0.0f;

    // per-lane row base (row = m0 + wid*32 + lr; instr i adds i*4 rows)
    const char* gA = (const char*)A + ((size_t)(m0 + wid * 32 + lr) * K) * 2;
    const char* gB = (const char*)B + ((size_t)(n0 + wid * 32 + lr) * K) * 2;
    const size_t rowstep = (size_t)4 * K * 2;   // 4 rows per instr

    for (int k0 = kbase; k0 < kbase + kc; k0 += 128) {
        const size_t kb = (size_t)k0 * 2;
        #pragma unroll
        for (int i = 0; i < 8; i++) {
            const size_t src = kb + (size_t)i * rowstep + (size_t)(offe ^ ((i & 1) << 6));
            __builtin_amdgcn_global_load_lds(
                (const __attribute__((address_space(1))) void*)(gA + src),
                (__attribute__((address_space(3))) void*)(&lsA[(wid * 8 + i) * 512]),
                16, 0, 0);
            __builtin_amdgcn_global_load_lds(
                (const __attribute__((address_space(1))) void*)(gB + src),
                (__attribute__((address_space(3))) void*)(&lsB[(wid * 8 + i) * 512]),
                16, 0, 0);
        }
        __syncthreads();

        #pragma unroll
        for (int ks = 0; ks < 4; ks++) {
            bf16x8 bfrag[4], afrag[4];
            #pragma unroll
            for (int nt = 0; nt < 4; nt++) {
                int r = wn + nt * 16 + c16;
                int pc = (quad + ks * 4) ^ (r & 7);
                bfrag[nt] = *(const bf16x8*)((const char*)lsB + r * 256 + pc * 16);
            }
            #pragma unroll
            for (int mt = 0; mt < 4; mt++) {
                int r = wm + mt * 16 + c16;
                int pc = (quad + ks * 4) ^ (r & 7);
                afrag[mt] = *(const bf16x8*)((const char*)lsA + r * 256 + pc * 16);
            }
            #pragma unroll
            for (int mt = 0; mt < 4; mt++)
                #pragma unroll
                for (int nt = 0; nt < 4; nt++)
                    acc[mt][nt] = __builtin_amdgcn_mfma_f32_16x16x32_bf16(
                        afrag[mt], bfrag[nt], acc[mt][nt], 0, 0, 0);
        }
        __syncthreads();
    }

    // epilogue.  C/D layout: col = lane&15, row = (lane>>4)*4 + reg
    #pragma unroll
    for (int mt = 0; mt < 4; mt++) {
        const int gm0 = m0 + wm + mt * 16 + quad * 4;   // 4 consecutive rows
        #pragma unroll
        for (int nt = 0; nt < 4; nt++) {
            const int gn = n0 + wn + nt * 16 + c16;
            f32x4 v = acc[mt][nt];
            if (MODE == 0) {
                us4 o;
                o.x = f2bf(v.x); o.y = f2bf(v.y); o.z = f2bf(v.z); o.w = f2bf(v.w);
                *(us4*)((unsigned short*)C + (size_t)gn * ldc + gm0) = o;
            } else {
                unsigned short* o = (unsigned short*)C + (size_t)blockIdx.z * PSTRIDE
                                  + (size_t)gm0 * ldc + gn;
                o[0]               = f2bf(v.x);
                o[ldc]             = f2bf(v.y);
                o[2 * (size_t)ldc] = f2bf(v.z);
                o[3 * (size_t)ldc] = f2bf(v.w);
            }
        }
    }
}

// T2[j][i] = bf16(ds[i] * sum_z P[z][j][i]).  P: NPART bf16 partials [512 x 4096].
__global__ void ep2_kernel(const unsigned short* __restrict__ P, const float* __restrict__ ds,
                           unsigned short* __restrict__ T2) {
    int t = blockIdx.x * 256 + threadIdx.x;
    int e = t << 2;
    int i = e & 4095;                  // column index
    f32x4 v = us4tof(((const us4*)P)[t]);
    #pragma unroll
    for (int z = 1; z < NPART; z++)
        v += us4tof(((const us4*)(P + (size_t)z * PSTRIDE))[t]);
    f32x4 d = *(const f32x4*)(ds + i);
    us4 o;
    o.x = f2bf(v.x * d.x); o.y = f2bf(v.y * d.y);
    o.z = f2bf(v.z * d.z); o.w = f2bf(v.w * d.w);
    ((us4*)T2)[t] = o;
}

// out[i][j] = relu(ds[i] * sum_z Q[z][i][j]).  Q: NPART bf16 partials [4096 x 512].
__global__ void ep3_kernel(const unsigned short* __restrict__ Q, const float* __restrict__ ds,
                           float* __restrict__ out) {
    int t = blockIdx.x * 256 + threadIdx.x;
    int e = t << 2;
    int i = e >> 9;                    // row index
    float s = ds[i];
    f32x4 v = us4tof(((const us4*)Q)[t]);
    #pragma unroll
    for (int z = 1; z < NPART; z++)
        v += us4tof(((const us4*)(Q + (size_t)z * PSTRIDE))[t]);
    f32x4 o;
    o.x = fmaxf(v.x * s, 0.0f); o.y = fmaxf(v.y * s, 0.0f);
    o.z = fmaxf(v.z * s, 0.0f); o.w = fmaxf(v.w * s, 0.0f);
    ((f32x4*)out)[t] = o;
}

extern "C" void kernel_launch(void* const* d_in, const int* in_sizes, int n_in,
                              void* d_out, int out_size, void* d_ws, size_t ws_size,
                              hipStream_t stream) {
    const float* X = (const float*)d_in[0];   // [4096 x 512]
    const float* A = (const float*)d_in[1];   // [4096 x 4096]
    const float* W = (const float*)d_in[2];   // [512 x 512]

    char* ws = (char*)d_ws;
    float*          dsc  = (float*)ws;                           // 16 KB
    unsigned short* A2   = (unsigned short*)(ws + 16384);        // 32 MB   bf16 A+I
    unsigned short* Xb   = (unsigned short*)(ws + 33570816u);    // 4 MB
    unsigned short* Wb   = (unsigned short*)(ws + 37765120u);    // 512 KB
    unsigned short* Yt   = (unsigned short*)(ws + 38289408u);    // 4 MB    (X@W^T)^T  [512][4096]
    unsigned short* T2   = (unsigned short*)(ws + 42483712u);    // 4 MB    ds*(A2@Y) transposed [512][4096]
    unsigned short* Part = (unsigned short*)(ws + 46678016u);    // 16 MB   NPART x bf16 split-K partials

    prep_kernel<<<18704, 256, 0, stream>>>(A, X, W, A2, Xb, Wb, dsc);

    // Yt = (Xb @ Wb^T)^T  [512][4096] bf16.  M=4096 (32 m-tiles = grid-x), N=512 (4 n-tiles).
    gemm_bt<0, 0><<<dim3(32, 4, 1), 256, 0, stream>>>(Xb, Wb, Yt, 512, 512, 4096);
    // Part[z][512][4096] = Yt @ A2^T bf16 partials (M=512: 4 m-tiles=y; N=4096: 32 n-tiles=x; z=4).
    gemm_bt<2, 1><<<dim3(32, 4, NPART), 256, 0, stream>>>(Yt, A2, Part, 4096, 4096 / NPART, 4096);
    // T2 = bf16(ds_col * sum_z Part[z]).
    ep2_kernel<<<2048, 256, 0, stream>>>(Part, dsc, T2);
    // Part[z][4096][512] = A2 @ T2^T bf16 partials (M=4096: 32 m-tiles=x; N=512: 4 n-tiles=y; z=4).
    gemm_bt<2, 0><<<dim3(32, 4, NPART), 256, 0, stream>>>(A2, T2, Part, 4096, 4096 / NPART, 512);
    // out = relu(ds_row * sum_z Part[z])  [4096 x 512] fp32.
    ep3_kernel<<<2048, 256, 0, stream>>>(Part, dsc, (float*)d_out);
}